// Round 8
// baseline (258.522 us; speedup 1.0000x reference)
//
#include <hip/hip_runtime.h>
#include <math.h>

#define GSZ 52
#define NA 3
#define NCLS 80
#define CH 85                     // 5 + NCLS
#define NCA (GSZ*GSZ*NA)          // 8112 cell-anchors per batch
#define MAXGT 64
#define RPW 16                    // records per wave (8112 % 16 == 0 -> batch-uniform waves)
#define FPW (RPW*CH)              // 1360 floats per tensor per wave
#define F4W (FPW/4)               // 340 float4 per tensor per wave (16B-aligned: 5440B chunks)

__device__ __forceinline__ float softplus_fast(float x) {
    return fmaxf(x, 0.0f) + __logf(1.0f + __expf(-fabsf(x)));
}

// component select + wave broadcast; e/src are literal constants at every call
// site -> folds to a single ds_bpermute after inlining.
__device__ __forceinline__ float bcast_f(float4 v, int e, int src) {
    float x = (e == 0) ? v.x : (e == 1) ? v.y : (e == 2) ? v.z : v.w;
    return __shfl(x, src, 64);
}
#define BCF(V, l) bcast_f(V[(l) >> 8], (l) & 3, ((l) >> 2) & 63)

__device__ __forceinline__ float elemf(float4 v, int e) {
    return (e == 0) ? v.x : (e == 1) ? v.y : (e == 2) ? v.z : v.w;
}

// ws layout: cnt[32] ints @0 | accum[8] floats @128 | done int @160 | gtbox @256
__global__ void k_init(int* ws32) {
    if (threadIdx.x < 48) ws32[threadIdx.x] = 0;
}

// Barrier-free streaming kernel: each wave owns 16 whole records of BOTH
// tensors in registers (12 float4 loads/lane, no LDS, no __syncthreads).
// Record-level fields (ch0-4) extracted via compile-time-constant shuffles;
// obj-conf + class BCE computed elementwise in place, gated by a
// wave-uniform obj bitmask (93% of waves skip via execz).
#define REC(r) { \
    float tx = BCF(T, 85*(r)+0), ty = BCF(T, 85*(r)+1); \
    float tw = BCF(T, 85*(r)+2), th = BCF(T, 85*(r)+3); \
    float tc = BCF(T, 85*(r)+4); \
    float q0 = BCF(P, 85*(r)+0), q1 = BCF(P, 85*(r)+1); \
    float q2 = BCF(P, 85*(r)+2), q3 = BCF(P, 85*(r)+3); \
    float q4 = BCF(P, 85*(r)+4); \
    int nn = n0 + (r); \
    int nl = nloc0 + (r); \
    int a = nl % NA; int cell = nl / NA; \
    int gi = cell / GSZ, gj = cell % GSZ; \
    float aw = (a == 0) ? an0.x : (a == 1) ? an1.x : an2.x; \
    float ah = (a == 0) ? an0.y : (a == 1) ? an1.y : an2.y; \
    float sx = __builtin_amdgcn_rcpf(1.f + __expf(-q0)); \
    float sy = __builtin_amdgcn_rcpf(1.f + __expf(-q1)); \
    float bw = __expf(q2) * aw, bh = __expf(q3) * ah; \
    bool iso = tc > 0.f; \
    if (iso) objm |= (1u << (r)); \
    if (lane == (r)) { \
        boxout[nn]  = make_float4((sx + (float)gj) * 8.f, (sy + (float)gi) * 8.f, \
                                  iso ? -bw : bw, bh); \
        confout[nn] = q4; \
        if (iso) { \
            int pos = atomicAdd(&cnt[b], 1); \
            if (pos < MAXGT) gtbox[b * MAXGT + pos] = make_float4(tx, ty, tw, th); \
            float scale = 2.f - (tw * (1.f/416.f)) * (th * (1.f/416.f)); \
            float dx = sx - (tx * 0.125f - (float)gj); \
            float dy = sy - (ty * 0.125f - (float)gi); \
            a_txty += (dx * dx + dy * dy) * scale; \
            float rw = __builtin_amdgcn_rcpf(aw), rh2 = __builtin_amdgcn_rcpf(ah); \
            float pwr = fminf(fmaxf(bw * rw,  1e-9f), 1e9f); \
            float phr = fminf(fmaxf(bh * rh2, 1e-9f), 1e9f); \
            float twr = fminf(fmaxf(tw * rw,  1e-9f), 1e9f); \
            float thr = fminf(fmaxf(th * rh2, 1e-9f), 1e9f); \
            float dw = __logf(pwr) - __logf(twr); \
            float dh = __logf(phr) - __logf(thr); \
            a_twth += (dw * dw + dh * dh) * scale; \
        } \
    } \
}

__global__ void kA(const float* __restrict__ tg, const float* __restrict__ pr,
                   const float* __restrict__ anchors,
                   int* __restrict__ cnt, float* __restrict__ accum,
                   float4* __restrict__ gtbox,
                   float4* __restrict__ boxout, float* __restrict__ confout) {
    const int tid  = threadIdx.x;
    const int lane = tid & 63;
    const int W    = blockIdx.x * 4 + (tid >> 6);     // global wave id
    const int n0   = W * RPW;                         // first global record
    const int b    = n0 / NCA;                        // wave-uniform batch
    const int nloc0 = n0 - b * NCA;

    // ---- load 16 records of both tensors into registers (no LDS) ----
    const float4* gT = (const float4*)tg;
    const float4* gP = (const float4*)pr;
    size_t g4 = (size_t)W * F4W;
    float4 T[6], P[6];
    T[5] = make_float4(0.f, 0.f, 0.f, 0.f);
    P[5] = make_float4(0.f, 0.f, 0.f, 0.f);
#pragma unroll
    for (int i = 0; i < 5; i++) {
        T[i] = gT[g4 + 64 * i + lane];
        P[i] = gP[g4 + 64 * i + lane];
    }
    if (lane < F4W - 320) {                           // lane < 20
        T[5] = gT[g4 + 320 + lane];
        P[5] = gP[g4 + 320 + lane];
    }

    const float2 an0 = ((const float2*)anchors)[0];
    const float2 an1 = ((const float2*)anchors)[1];
    const float2 an2 = ((const float2*)anchors)[2];

    float a_txty = 0.f, a_twth = 0.f, a_obj = 0.f, a_cls = 0.f;
    unsigned objm = 0;

    // ---- record-level extraction/decode (compile-time shuffle positions) ----
    REC(0)  REC(1)  REC(2)  REC(3)  REC(4)  REC(5)  REC(6)  REC(7)
    REC(8)  REC(9)  REC(10) REC(11) REC(12) REC(13) REC(14) REC(15)

    // ---- elementwise obj-conf + class BCE, wave-uniform gate ----
    if (objm) {
#pragma unroll
        for (int i = 0; i < 6; i++) {
            int l0 = 256 * i + 4 * lane;
            if (l0 < FPW) {
                int rr = l0 / 85;
                int c0 = l0 - 85 * rr;
#pragma unroll
                for (int e = 0; e < 4; e++) {
                    float t = elemf(T[i], e), p = elemf(P[i], e);
                    int c = c0 + e, r2 = rr;
                    if (c >= 85) { c -= 85; r2++; }
                    if (c == 4) {
                        if (t > 0.f) a_obj += softplus_fast(p) - p;   // t == 1 exactly
                    } else if (c >= 5 && ((objm >> r2) & 1)) {
                        a_cls += softplus_fast(p) - p * t;
                    }
                }
            }
        }
    }

    // ---- wave reduce 4 partials, lane 0 atomics (guarded; rare) ----
    for (int off = 32; off > 0; off >>= 1) {
        a_txty += __shfl_down(a_txty, off);
        a_twth += __shfl_down(a_twth, off);
        a_obj  += __shfl_down(a_obj,  off);
        a_cls  += __shfl_down(a_cls,  off);
    }
    if (lane == 0 && (a_txty != 0.f || a_twth != 0.f || a_obj != 0.f || a_cls != 0.f)) {
        atomicAdd(&accum[0], a_txty);
        atomicAdd(&accum[1], a_twth);
        atomicAdd(&accum[3], a_obj);
        atomicAdd(&accum[4], a_cls);
    }
}

// noobj loss over compact SoA + final output write via last-block ticket.
__global__ __launch_bounds__(256)
void kB(const int* __restrict__ cnt, const float4* __restrict__ gtbox,
        const float4* __restrict__ boxin, const float* __restrict__ confin,
        float* __restrict__ accum, int* __restrict__ done, int B,
        float* __restrict__ out) {
    __shared__ float4 sbox[2 * MAXGT];
    __shared__ float  sw[4];
    __shared__ int    sm[2];

    int tid = threadIdx.x;
    size_t rec = (size_t)blockIdx.x * 256 + tid;       // grid*256 == B*NCA
    int b0 = (int)(((size_t)blockIdx.x * 256) / NCA);
    int b1 = (int)(((size_t)blockIdx.x * 256 + 255) / NCA);

    if (tid < MAXGT)          sbox[tid] = gtbox[b0 * MAXGT + tid];
    else if (tid < 2 * MAXGT) sbox[tid] = gtbox[b1 * MAXGT + (tid - MAXGT)];
    if (tid == 0) { sm[0] = min(cnt[b0], MAXGT); sm[1] = min(cnt[b1], MAXGT); }
    __syncthreads();

    int b = (int)(rec / NCA);
    int base = (b == b0) ? 0 : MAXGT;
    int m    = (b == b0) ? sm[0] : sm[1];

    float4 pb = boxin[rec];
    float pconf = confin[rec];
    float v = 0.f;
    if (pb.z > 0.f) {                                  // non-obj cell
        float bw = pb.z, bh = pb.w;
        float px0 = pb.x - bw * 0.5f, px1 = pb.x + bw * 0.5f;
        float py0 = pb.y - bh * 0.5f, py1 = pb.y + bh * 0.5f;
        float areap = bw * bh;
        float best = 0.f;
        for (int k = 0; k < m; k++) {
            float4 q = sbox[base + k];
            float ix = fminf(px1, q.x + q.z * 0.5f) - fmaxf(px0, q.x - q.z * 0.5f);
            float iy = fminf(py1, q.y + q.w * 0.5f) - fmaxf(py0, q.y - q.w * 0.5f);
            float inter = fmaxf(ix, 0.f) * fmaxf(iy, 0.f);
            float u = areap + q.z * q.w - inter + 1e-9f;
            best = fmaxf(best, inter * __builtin_amdgcn_rcpf(u));
        }
        if (best < 0.6f) v = softplus_fast(pconf);
    }

    int lane = tid & 63, wv = tid >> 6;
    for (int off = 32; off > 0; off >>= 1) v += __shfl_down(v, off);
    if (lane == 0) sw[wv] = v;
    __syncthreads();
    if (tid == 0) {
        atomicAdd(&accum[2], sw[0] + sw[1] + sw[2] + sw[3]);
        __threadfence();
        int t = atomicAdd(done, 1);
        if (t == (int)gridDim.x - 1) {                 // last block finalizes
            float invB = 1.f / (float)B;
            float tot = 0.f;
#pragma unroll
            for (int i = 0; i < 5; i++) {
                float r = atomicAdd(&accum[i], 0.f) * invB;
                out[i] = r;
                tot += r;
            }
            out[5] = tot;
        }
    }
}

extern "C" void kernel_launch(void* const* d_in, const int* in_sizes, int n_in,
                              void* d_out, int out_size, void* d_ws, size_t ws_size,
                              hipStream_t stream) {
    const float* preds   = (const float*)d_in[0];
    const float* targets = (const float*)d_in[1];
    const float* anchors = (const float*)d_in[2];
    float* out = (float*)d_out;

    int B = in_sizes[0] / (NCA * CH);                 // 32
    size_t total_rec = (size_t)B * NCA;               // 259584

    char* ws = (char*)d_ws;
    int*    cnt   = (int*)ws;                         // 32 ints  @0
    float*  accum = (float*)(ws + 128);               // 8 floats @128
    int*    done  = (int*)(ws + 160);                 // 1 int    @160
    float4* gtbox = (float4*)(ws + 256);              // B*64 float4
    size_t off = 256 + (size_t)B * MAXGT * sizeof(float4);
    off = (off + 15) & ~(size_t)15;
    float4* boxout  = (float4*)(ws + off);  off += total_rec * sizeof(float4);
    float*  confout = (float*)(ws + off);

    int waves = (int)(total_rec / RPW);               // 16224
    int gA = waves / 4;                               // 4056 blocks (4 waves each)
    int gB = (int)(total_rec / 256);                  // 1014

    k_init<<<1, 64, 0, stream>>>((int*)ws);
    kA<<<gA, 256, 0, stream>>>(targets, preds, anchors, cnt, accum,
                               gtbox, boxout, confout);
    kB<<<gB, 256, 0, stream>>>(cnt, gtbox, boxout, confout, accum, done, B, out);
}